// Round 20
// baseline (147.505 us; speedup 1.0000x reference)
//
#include <hip/hip_runtime.h>
#include <math.h>

#define BB 4
#define NN 2048
#define MM 8192
#define EPSF 1e-5f
#define LDC 1376   // concat stride: onehot16 | pf0 64 | pf1 128 | pf2 128 | pf3 1024 | pad16

typedef _Float16 half8 __attribute__((ext_vector_type(8)));
typedef float f32x4 __attribute__((ext_vector_type(4)));

__device__ __forceinline__ unsigned short f2h(float x) {
    _Float16 h = (_Float16)x;
    return __builtin_bit_cast(unsigned short, h);
}
__device__ __forceinline__ float h2f(unsigned short u) {
    return (float)__builtin_bit_cast(_Float16, u);
}
// order-preserving float<->unsigned for atomicMax over signed floats
__device__ __forceinline__ unsigned fflip(float x) {
    unsigned u = __builtin_bit_cast(unsigned, x);
    return (u >> 31) ? ~u : (u | 0x80000000u);
}
__device__ __forceinline__ float funflip(unsigned s) {
    unsigned u = (s >> 31) ? (s ^ 0x80000000u) : ~s;
    return __builtin_bit_cast(float, u);
}
#define FLIP_NEG_INF 0x007FFFFFu

__device__ __forceinline__ float angle3(float ux, float uy, float uz,
                                        float vx, float vy, float vz) {
    float crx = uy * vz - uz * vy;
    float cry = uz * vx - ux * vz;
    float crz = ux * vy - uy * vx;
    float s = sqrtf(crx * crx + cry * cry + crz * crz);
    float c = ux * vx + uy * vy + uz * vz;
    return atan2f(s, c);
}

// BN coefficient from a sums slice
__device__ __forceinline__ void bncoef(const float* __restrict__ sums,
                                       const float* __restrict__ g,
                                       const float* __restrict__ bb,
                                       int o, float& a, float& c) {
    float mu = sums[o] * (1.f / 8192.f);
    float var = sums[1024 + o] * (1.f / 8192.f) - mu * mu;
    var = fmaxf(var, 0.f);
    a = g[o] * (1.0f / sqrtf(var + EPSF));
    c = bb[o] - mu * a;
}

// ---------------------------------------------------------------------------
// fused preamble: wconv x4 (0..863) | stats (864..867) | init SUMS/MAXB/CONTRIB
// (868..943; MAXB gets flip(-inf)) | onehot+pad (944..975)
// ---------------------------------------------------------------------------
__global__ __launch_bounds__(256) void prep_k(const float* __restrict__ in,
                                              const float* __restrict__ w1, const float* __restrict__ w2,
                                              const float* __restrict__ w3, const float* __restrict__ w4,
                                              const float* __restrict__ w5, const float* __restrict__ w6,
                                              const float* __restrict__ w7,
                                              unsigned short* __restrict__ Wb,
                                              float* __restrict__ st,
                                              unsigned* __restrict__ zp,
                                              unsigned short* __restrict__ XCb) {
    int blk = blockIdx.x;
    int t = threadIdx.x;
    if (blk < 864) {
        int idx0 = blk * 1024 + t * 4;
        ushort4 r;
        unsigned short* rp = (unsigned short*)&r;
        #pragma unroll
        for (int e = 0; e < 4; ++e) {
            int idx = idx0 + e;
            unsigned short v;
            if (idx < 8192) v = f2h(w1[idx]);
            else if (idx < 24576) v = f2h(w2[idx - 8192]);
            else if (idx < 155648) v = f2h(w3[idx - 24576]);
            else if (idx < 507904) {
                int l = idx - 155648;
                int o = l / 1376, k = l - o * 1376;
                v = (k < 1360) ? f2h(w4[o * 2384 + k]) : (unsigned short)0;
            } else if (idx < 573440) v = f2h(w5[idx - 507904]);
            else if (idx < 606208) v = f2h(w6[idx - 573440]);
            else if (idx < 614400) {
                int l = idx - 606208;
                int o = l >> 7, k = l & 127;
                v = (o < 50) ? f2h(w7[o * 128 + k]) : (unsigned short)0;
            } else {
                int l = idx - 614400;
                int c = l >> 8, o = l & 255;
                v = (c < 1024) ? f2h(w4[o * 2384 + 1360 + c]) : (unsigned short)0;
            }
            rp[e] = v;
        }
        *(ushort4*)&Wb[idx0] = r;
    } else if (blk < 868) {
        int b = blk - 864;
        const float* base = in + (size_t)b * 22 * NN;
        float cs0 = 0.f, cs1 = 0.f, cs2 = 0.f, ns0 = 0.f, ns1 = 0.f, ns2 = 0.f;
        for (int n = t; n < NN; n += 256) {
            float cx = base[0 * NN + n], cy = base[1 * NN + n], cz = base[2 * NN + n];
            float nx = base[3 * NN + n], ny = base[4 * NN + n], nz = base[5 * NN + n];
            float inv = 1.0f / sqrtf(nx * nx + ny * ny + nz * nz);
            cs0 += cx; cs1 += cy; cs2 += cz;
            ns0 += nx * inv; ns1 += ny * inv; ns2 += nz * inv;
        }
        __shared__ float red[6][256];
        red[0][t] = cs0; red[1][t] = cs1; red[2][t] = cs2;
        red[3][t] = ns0; red[4][t] = ns1; red[5][t] = ns2;
        __syncthreads();
        for (int s = 128; s > 0; s >>= 1) {
            if (t < s) {
                #pragma unroll
                for (int i = 0; i < 6; ++i) red[i][t] += red[i][t + s];
            }
            __syncthreads();
        }
        if (t == 0) {
            float ccx = red[0][0] / (float)NN, ccy = red[1][0] / (float)NN, ccz = red[2][0] / (float)NN;
            float cnx = red[3][0] / (float)NN, cny = red[4][0] / (float)NN, cnz = red[5][0] / (float)NN;
            float inv = 1.0f / sqrtf(cnx * cnx + cny * cny + cnz * cnz);
            float* s9 = st + b * 16;
            s9[0] = ccx; s9[1] = ccy; s9[2] = ccz;
            s9[3] = cnx; s9[4] = cny; s9[5] = cnz;
            s9[6] = cnx * inv; s9[7] = cny * inv; s9[8] = cnz * inv;
        }
    } else if (blk < 944) {
        int idx = (blk - 868) * 256 + t;
        zp[idx] = (idx >= 14336 && idx < 18432) ? FLIP_NEG_INF : 0u;
    } else {
        int m = (blk - 944) * 256 + t;
        int b = m >> 11, n = m & (NN - 1);
        const float* src = in + (size_t)b * 22 * NN + 6 * NN + n;
        unsigned short vals[16];
        #pragma unroll
        for (int r = 0; r < 16; ++r) vals[r] = f2h(src[(size_t)r * NN]);
        ushort4* dst = (ushort4*)&XCb[(size_t)m * LDC];
        #pragma unroll
        for (int q = 0; q < 4; ++q)
            dst[q] = make_ushort4(vals[4 * q], vals[4 * q + 1], vals[4 * q + 2], vals[4 * q + 3]);
        ushort4 z = make_ushort4(0, 0, 0, 0);
        ushort4* pz = (ushort4*)&XCb[(size_t)m * LDC + 1360];
        pz[0] = z; pz[1] = z; pz[2] = z; pz[3] = z;
    }
}

// ---------------------------------------------------------------------------
// per-point PPF + packed projected vectors PQ = (x,y,z,|P|)
// ---------------------------------------------------------------------------
__global__ __launch_bounds__(256) void point_k(const float* __restrict__ in,
                                               const float* __restrict__ st,
                                               float4* __restrict__ PQ,
                                               float* __restrict__ F0) {
    int idx = blockIdx.x * 256 + threadIdx.x;
    int b = idx >> 11, n = idx & (NN - 1);
    const float* base = in + (size_t)b * 22 * NN;
    const float* s9 = st + b * 16;
    float cx = base[0 * NN + n], cy = base[1 * NN + n], cz = base[2 * NN + n];
    float nx = base[3 * NN + n], ny = base[4 * NN + n], nz = base[5 * NN + n];
    float inv = 1.0f / sqrtf(nx * nx + ny * ny + nz * nz);
    nx *= inv; ny *= inv; nz *= inv;
    float ccx = s9[0], ccy = s9[1], ccz = s9[2];
    float cnx = s9[3], cny = s9[4], cnz = s9[5];
    float ex = s9[6], ey = s9[7], ez = s9[8];
    float dx = cx - ccx, dy = cy - ccy, dz = cz - ccz;
    F0[0 * MM + idx] = angle3(cnx, cny, cnz, dx, dy, dz);
    F0[1 * MM + idx] = angle3(nx, ny, nz, dx, dy, dz);
    F0[2 * MM + idx] = angle3(cnx, cny, cnz, nx, ny, nz);
    F0[3 * MM + idx] = sqrtf(dx * dx + dy * dy + dz * dz);
    float dot = dx * ex + dy * ey + dz * ez;
    float px = dx - dot * cnx;
    float py = dy - dot * cny;
    float pz = dz - dot * cnz;
    PQ[idx] = make_float4(px, py, pz, sqrtf(px * px + py * py + pz * pz));
}

// ---------------------------------------------------------------------------
// per-row median via two-pass LDS histogram with algebraic fp16 key.
// NEW (R20): 512-thread block = 8 waves = 8 rows sharing ONE 32KB LDS tile
// of the batch's PQ (loaded cooperatively once) — cuts the per-row 32KB
// L1 re-read 8x; key loop reads conflict-free ds_read_b128 from the tile.
// Histogram/scan/key math identical to R19 (bit-identical result).
// LDS: 32KB tile + 8x1KB hists = 40KB -> 4 blocks/CU, ~32 waves/CU.
// ---------------------------------------------------------------------------
__global__ __launch_bounds__(512) void alpha_k(const float4* __restrict__ PQ,
                                               float* __restrict__ F0) {
    __shared__ float4 tile[NN];          // 32KB
    __shared__ unsigned hist[8][256];    // 8KB
    int t = threadIdx.x;
    int wv = t >> 6;
    int lane = t & 63;
    int row = blockIdx.x * 8 + wv;
    int b = row >> 11;
    const float4* base = PQ + (size_t)b * NN;
    #pragma unroll
    for (int i = 0; i < 4; ++i)
        tile[t + 512 * i] = base[t + 512 * i];
    __syncthreads();
    float4 a = tile[row & (NN - 1)];
    unsigned u[16];
    #pragma unroll
    for (int c = 0; c < 4; ++c) {
        #pragma unroll
        for (int j = 0; j < 4; ++j) {
            int s2 = c * 8 + j * 2;
            float4 bv0 = tile[s2 * 64 + lane];
            float4 bv1 = tile[(s2 + 1) * 64 + lane];
            float k0, k1;
            {
                float dc = a.x * bv0.x + a.y * bv0.y + a.z * bv0.z;
                float h = a.w * bv0.w;
                float rc = __builtin_amdgcn_rcpf(h + dc);
                k0 = (h - dc) * rc;
                if (k0 <= 2e-7f) k0 = __builtin_inff();
            }
            {
                float dc = a.x * bv1.x + a.y * bv1.y + a.z * bv1.z;
                float h = a.w * bv1.w;
                float rc = __builtin_amdgcn_rcpf(h + dc);
                k1 = (h - dc) * rc;
                if (k1 <= 2e-7f) k1 = __builtin_inff();
            }
            u[c * 4 + j] = (unsigned)f2h(k0) | ((unsigned)f2h(k1) << 16);
        }
        asm volatile("" ::: "memory");
    }
    unsigned* h = hist[wv];
    h[lane] = 0; h[lane + 64] = 0; h[lane + 128] = 0; h[lane + 192] = 0;
    __syncthreads();
    #pragma unroll
    for (int q = 0; q < 16; ++q) {
        atomicAdd(&h[(u[q] & 0xFFFFu) >> 7], 1u);
        atomicAdd(&h[u[q] >> 23], 1u);
    }
    __syncthreads();
    const unsigned K = 1023;
    unsigned h0 = h[4 * lane], h1 = h[4 * lane + 1], h2 = h[4 * lane + 2], h3 = h[4 * lane + 3];
    unsigned lsum = h0 + h1 + h2 + h3;
    unsigned inc = lsum;
    #pragma unroll
    for (int d = 1; d < 64; d <<= 1) {
        unsigned tv = __shfl_up(inc, d);
        if (lane >= d) inc += tv;
    }
    unsigned excl = inc - lsum;
    bool has = (excl <= K) && (K < inc);
    unsigned long long mask = __ballot(has);
    int L = __ffsll((long long)mask) - 1;
    unsigned packed = 0;
    if (has) {
        unsigned e = excl, Bq = 4 * lane;
        if (e + h0 <= K) { e += h0; Bq++;
            if (e + h1 <= K) { e += h1; Bq++;
                if (e + h2 <= K) { e += h2; Bq++; } } }
        packed = (Bq << 16) | e;
    }
    packed = __shfl(packed, L);
    unsigned B = packed >> 16;
    unsigned k2 = K - (packed & 0xFFFFu);
    __syncthreads();
    h[lane] = 0; h[lane + 64] = 0;
    __syncthreads();
    #pragma unroll
    for (int q = 0; q < 16; ++q) {
        unsigned lo = u[q] & 0xFFFFu, hi = u[q] >> 16;
        if ((lo >> 7) == B) atomicAdd(&h[lo & 127], 1u);
        if ((hi >> 7) == B) atomicAdd(&h[hi & 127], 1u);
    }
    __syncthreads();
    unsigned g0 = h[2 * lane], g1 = h[2 * lane + 1];
    unsigned ls2 = g0 + g1, inc2 = ls2;
    #pragma unroll
    for (int d = 1; d < 64; d <<= 1) {
        unsigned tv = __shfl_up(inc2, d);
        if (lane >= d) inc2 += tv;
    }
    unsigned excl2 = inc2 - ls2;
    bool has2 = (excl2 <= k2) && (k2 < inc2);
    unsigned long long m2 = __ballot(has2);
    int L2 = __ffsll((long long)m2) - 1;
    unsigned low = 0;
    if (has2) low = 2 * lane + ((excl2 + g0 <= k2) ? 1u : 0u);
    low = __shfl(low, L2);
    unsigned T = (B << 7) | low;
    if (lane == 0) {
        float lo = h2f((unsigned short)T);
        float hi = h2f((unsigned short)(T + 1));
        F0[4 * MM + row] = 2.0f * atanf(sqrtf(0.5f * (lo + hi)));
    }
}

// ---------------------------------------------------------------------------
// pf0 + fused BN stats: raw fp16 into XCb+16; stats -> sums.
// ---------------------------------------------------------------------------
__global__ __launch_bounds__(256) void pf0s_k(const float* __restrict__ F0,
                                              const float* __restrict__ W,
                                              unsigned short* __restrict__ dst,
                                              float* __restrict__ sums) {
    __shared__ float ws[320];
    int t = threadIdx.x;
    for (int i = t; i < 320; i += 256) ws[i] = W[i];
    __syncthreads();
    int ol = t & 63, mg = t >> 6;
    int m0 = blockIdx.x * 512;
    float w0 = ws[ol * 5], w1 = ws[ol * 5 + 1], w2 = ws[ol * 5 + 2], w3 = ws[ol * 5 + 3], w4 = ws[ol * 5 + 4];
    float s = 0.f, q = 0.f;
    for (int i = 0; i < 128; ++i) {
        int m = m0 + i * 4 + mg;
        float y = w0 * F0[m] + w1 * F0[MM + m] + w2 * F0[2 * MM + m]
                + w3 * F0[3 * MM + m] + w4 * F0[4 * MM + m];
        dst[(size_t)m * LDC + ol] = f2h(y);
        s += y; q += y * y;
    }
    __shared__ float ls[4][64], lq[4][64];
    ls[mg][ol] = s; lq[mg][ol] = q;
    __syncthreads();
    if (mg == 0) {
        s = ls[0][ol] + ls[1][ol] + ls[2][ol] + ls[3][ol];
        q = lq[0][ol] + lq[1][ol] + lq[2][ol] + lq[3][ol];
        atomicAdd(&sums[ol], s);
        atomicAdd(&sums[1024 + ol], q);
    }
}

// ---------------------------------------------------------------------------
// fp16 MFMA GEMM, 128x128 block tile, 4 waves (2x2), each wave 64x64
// (4x4 16x16x32 frags -> 16 MFMA : 8 ds_read_b128).
// TRANS: 0 none, 1 uniform (xs,xg,xb), 2 AB4 table (cls0).
// MODE: 1 raw fp16 out (yld) + stats [+DOMAX raw channel max]; 2 K-split partial.
// ---------------------------------------------------------------------------
template<int MODE, int TRANS, int DOMAX>
__global__ __launch_bounds__(256) void mgemm128_k(const unsigned short* __restrict__ X, int ldx,
                                                  const unsigned short* __restrict__ W, int ldw,
                                                  unsigned short* __restrict__ Yh, int yld, int Co, int K, int kchunk,
                                                  float* __restrict__ sums,
                                                  const float* __restrict__ xs, const float* __restrict__ xg,
                                                  const float* __restrict__ xb,
                                                  const float4* __restrict__ AB4,
                                                  unsigned* __restrict__ maxbu) {
    __shared__ unsigned short As[128 * 32];   // 8KB
    __shared__ unsigned short Bs[128 * 32];   // 8KB
    __shared__ float4 ABl[352];
    int t = threadIdx.x;
    int mBase = blockIdx.x * 128;
    int oBase = blockIdx.y * 128;
    int k0c = blockIdx.z * kchunk;
    int k1c = k0c + kchunk; if (k1c > K) k1c = K;
    if (TRANS == 1) {
        float* abf = (float*)ABl;
        for (int i = t; i < K; i += 256) {
            float a, c; bncoef(xs, xg, xb, i, a, c);
            abf[2 * i] = a; abf[2 * i + 1] = c;
        }
    } else if (TRANS == 2) {
        for (int i = t; i < k1c - k0c; i += 256) ABl[i] = AB4[k0c + i];
    }
    int lane = t & 63, w = t >> 6;
    int warpM = (w & 1) * 64, warpO = (w >> 1) * 64;
    f32x4 acc[4][4];
    #pragma unroll
    for (int i = 0; i < 4; ++i)
        #pragma unroll
        for (int j = 0; j < 4; ++j) acc[i][j] = (f32x4){0.f, 0.f, 0.f, 0.f};
    int lr = t >> 1;           // 0..127
    int lc = (t & 1) * 16;     // 0 or 16
    const unsigned short* Xp = X + (size_t)(mBase + lr) * ldx + lc;
    const unsigned short* Wp = W + (size_t)(oBase + lr) * ldw + lc;
    int ar0 = (warpM + (lane & 15)) * 32 + (lane >> 4) * 8;
    int br0 = (warpO + (lane & 15)) * 32 + (lane >> 4) * 8;
    uint4 xa0 = *(const uint4*)(Xp + k0c);
    uint4 xa1 = *(const uint4*)(Xp + k0c + 8);
    uint4 wb0 = *(const uint4*)(Wp + k0c);
    uint4 wb1 = *(const uint4*)(Wp + k0c + 8);
    for (int k = k0c; k < k1c; k += 32) {
        __syncthreads();
        uint4 xc0 = xa0, xc1 = xa1;
        if (TRANS == 1) {
            const float* abf = (const float*)ABl;
            unsigned short* p0 = (unsigned short*)&xc0;
            unsigned short* p1 = (unsigned short*)&xc1;
            int kb = k + lc;
            #pragma unroll
            for (int e = 0; e < 8; ++e) {
                p0[e] = f2h(fmaxf(abf[2 * (kb + e)] * h2f(p0[e]) + abf[2 * (kb + e) + 1], 0.f));
                p1[e] = f2h(fmaxf(abf[2 * (kb + 8 + e)] * h2f(p1[e]) + abf[2 * (kb + 8 + e) + 1], 0.f));
            }
        } else if (TRANS == 2) {
            unsigned short* p0 = (unsigned short*)&xc0;
            unsigned short* p1 = (unsigned short*)&xc1;
            int kb = k + lc - k0c;
            #pragma unroll
            for (int e = 0; e < 8; ++e) {
                float4 q0 = ABl[kb + e];
                float4 q1 = ABl[kb + 8 + e];
                p0[e] = f2h(fmaxf(q0.x * h2f(p0[e]) + q0.y, q0.z));
                p1[e] = f2h(fmaxf(q1.x * h2f(p1[e]) + q1.y, q1.z));
            }
        }
        *(uint4*)&As[lr * 32 + lc] = xc0;
        *(uint4*)&As[lr * 32 + lc + 8] = xc1;
        *(uint4*)&Bs[lr * 32 + lc] = wb0;
        *(uint4*)&Bs[lr * 32 + lc + 8] = wb1;
        if (k + 32 < k1c) {
            xa0 = *(const uint4*)(Xp + k + 32);
            xa1 = *(const uint4*)(Xp + k + 40);
            wb0 = *(const uint4*)(Wp + k + 32);
            wb1 = *(const uint4*)(Wp + k + 40);
        }
        __syncthreads();
        half8 af[4], bf[4];
        #pragma unroll
        for (int i = 0; i < 4; ++i) {
            af[i] = __builtin_bit_cast(half8, *(const uint4*)&As[ar0 + i * 16 * 32]);
            bf[i] = __builtin_bit_cast(half8, *(const uint4*)&Bs[br0 + i * 16 * 32]);
        }
        #pragma unroll
        for (int i = 0; i < 4; ++i)
            #pragma unroll
            for (int j = 0; j < 4; ++j)
                acc[i][j] = __builtin_amdgcn_mfma_f32_16x16x32_f16(af[i], bf[j], acc[i][j], 0, 0, 0);
    }
    unsigned short* Yp = Yh + (MODE == 2 ? (size_t)blockIdx.z * MM * yld : 0);
    #pragma unroll
    for (int i = 0; i < 4; ++i)
        #pragma unroll
        for (int j = 0; j < 4; ++j) {
            int m0 = mBase + warpM + i * 16 + (lane >> 4) * 4;
            int o = oBase + warpO + j * 16 + (lane & 15);
            #pragma unroll
            for (int r = 0; r < 4; ++r)
                Yp[(size_t)(m0 + r) * yld + o] = f2h(acc[i][j][r]);
        }
    if (MODE == 1) {
        __syncthreads();
        float* ssum = (float*)As;
        unsigned* smax = (unsigned*)As + 128;
        float* ssq = (float*)Bs;
        if (t < 128) { ssum[t] = 0.f; ssq[t] = 0.f; if (DOMAX) smax[t] = FLIP_NEG_INF; }
        __syncthreads();
        #pragma unroll
        for (int j = 0; j < 4; ++j) {
            int oc = warpO + j * 16 + (lane & 15);
            float s = 0.f, q = 0.f, mx = -__builtin_inff();
            #pragma unroll
            for (int i = 0; i < 4; ++i)
                #pragma unroll
                for (int r = 0; r < 4; ++r) {
                    float v = acc[i][j][r];
                    s += v; q += v * v; mx = fmaxf(mx, v);
                }
            atomicAdd(&ssum[oc], s);
            atomicAdd(&ssq[oc], q);
            if (DOMAX) atomicMax(&smax[oc], fflip(mx));
        }
        __syncthreads();
        if (t < 128) {
            atomicAdd(&sums[oBase + t], ssum[t]);
            atomicAdd(&sums[1024 + oBase + t], ssq[t]);
            if (DOMAX) atomicMax(&maxbu[(mBase >> 11) * 1024 + oBase + t], smax[t]);
        }
    }
}

// ---------------------------------------------------------------------------
// fp16 MFMA GEMM BM=64 BO=64 with staging-normalization.
// MODE 1: raw fp16 out (yld) + stats. MODE 3: direct (b,50,n) out + bias.
// ---------------------------------------------------------------------------
template<int MODE, int TRANS>
__global__ __launch_bounds__(256) void mgemm64_k(const unsigned short* __restrict__ X, int ldx,
                                                 const unsigned short* __restrict__ W, int ldw,
                                                 void* __restrict__ Yv, int yld, int Co, int K,
                                                 float* __restrict__ sums,
                                                 const float* __restrict__ xs, const float* __restrict__ xg,
                                                 const float* __restrict__ xb) {
    __shared__ unsigned short As[64 * 32];
    __shared__ unsigned short Bs[64 * 32];
    __shared__ float ABl[512];
    int t = threadIdx.x;
    int mBase = blockIdx.x * 64;
    int oBase = blockIdx.y * 64;
    if (TRANS == 1) {
        for (int i = t; i < K; i += 256) {
            float a, c; bncoef(xs, xg, xb, i, a, c);
            ABl[2 * i] = a; ABl[2 * i + 1] = c;
        }
    }
    int lane = t & 63, w = t >> 6;
    int warpM = (w & 1) * 32, warpO = (w >> 1) * 32;
    f32x4 acc[2][2];
    #pragma unroll
    for (int i = 0; i < 2; ++i)
        #pragma unroll
        for (int j = 0; j < 2; ++j) acc[i][j] = (f32x4){0.f, 0.f, 0.f, 0.f};
    int lr = t >> 2;
    int lc = (t & 3) * 8;
    const unsigned short* Xp = X + (size_t)(mBase + lr) * ldx + lc;
    const unsigned short* Wp = W + (size_t)(oBase + lr) * ldw + lc;
    int ar0 = (warpM + (lane & 15)) * 32 + (lane >> 4) * 8;
    int br0 = (warpO + (lane & 15)) * 32 + (lane >> 4) * 8;
    uint4 xa = *(const uint4*)(Xp);
    uint4 wb = *(const uint4*)(Wp);
    for (int k = 0; k < K; k += 32) {
        __syncthreads();
        uint4 xc = xa;
        if (TRANS == 1) {
            unsigned short* p = (unsigned short*)&xc;
            int kb = k + lc;
            #pragma unroll
            for (int e = 0; e < 8; ++e)
                p[e] = f2h(fmaxf(ABl[2 * (kb + e)] * h2f(p[e]) + ABl[2 * (kb + e) + 1], 0.f));
        }
        *(uint4*)&As[lr * 32 + lc] = xc;
        *(uint4*)&Bs[lr * 32 + lc] = wb;
        if (k + 32 < K) {
            xa = *(const uint4*)(Xp + k + 32);
            wb = *(const uint4*)(Wp + k + 32);
        }
        __syncthreads();
        half8 a0 = __builtin_bit_cast(half8, *(const uint4*)&As[ar0]);
        half8 a1 = __builtin_bit_cast(half8, *(const uint4*)&As[ar0 + 16 * 32]);
        half8 b0 = __builtin_bit_cast(half8, *(const uint4*)&Bs[br0]);
        half8 b1 = __builtin_bit_cast(half8, *(const uint4*)&Bs[br0 + 16 * 32]);
        acc[0][0] = __builtin_amdgcn_mfma_f32_16x16x32_f16(a0, b0, acc[0][0], 0, 0, 0);
        acc[0][1] = __builtin_amdgcn_mfma_f32_16x16x32_f16(a0, b1, acc[0][1], 0, 0, 0);
        acc[1][0] = __builtin_amdgcn_mfma_f32_16x16x32_f16(a1, b0, acc[1][0], 0, 0, 0);
        acc[1][1] = __builtin_amdgcn_mfma_f32_16x16x32_f16(a1, b1, acc[1][1], 0, 0, 0);
    }
    if (MODE == 3) {
        float* outp = (float*)Yv;
        #pragma unroll
        for (int i = 0; i < 2; ++i)
            #pragma unroll
            for (int j = 0; j < 2; ++j) {
                int m0 = mBase + warpM + i * 16 + (lane >> 4) * 4;
                int o = oBase + warpO + j * 16 + (lane & 15);
                if (o < 50) {
                    int bb2 = m0 >> 11, n = m0 & (NN - 1);
                    float bi = sums[o];
                    float4 v = make_float4(acc[i][j][0] + bi, acc[i][j][1] + bi,
                                           acc[i][j][2] + bi, acc[i][j][3] + bi);
                    *(float4*)&outp[((size_t)bb2 * 50 + o) * NN + n] = v;
                }
            }
    } else {
        unsigned short* Yh = (unsigned short*)Yv;
        #pragma unroll
        for (int i = 0; i < 2; ++i)
            #pragma unroll
            for (int j = 0; j < 2; ++j) {
                int m0 = mBase + warpM + i * 16 + (lane >> 4) * 4;
                int o = oBase + warpO + j * 16 + (lane & 15);
                #pragma unroll
                for (int r = 0; r < 4; ++r)
                    Yh[(size_t)(m0 + r) * yld + o] = f2h(acc[i][j][r]);
            }
        __syncthreads();
        float* ssum = (float*)As;
        float* ssq = (float*)Bs;
        if (t < 64) { ssum[t] = 0.f; ssq[t] = 0.f; }
        __syncthreads();
        #pragma unroll
        for (int j = 0; j < 2; ++j) {
            int oc = warpO + j * 16 + (lane & 15);
            float s = 0.f, q = 0.f;
            #pragma unroll
            for (int i = 0; i < 2; ++i)
                #pragma unroll
                for (int r = 0; r < 4; ++r) { float v = acc[i][j][r]; s += v; q += v * v; }
            atomicAdd(&ssum[oc], s);
            atomicAdd(&ssq[oc], q);
        }
        __syncthreads();
        if (t < 64) {
            atomicAdd(&sums[oBase + t], ssum[t]);
            atomicAdd(&sums[1024 + oBase + t], ssq[t]);
        }
    }
}

// ---------------------------------------------------------------------------
// fused: build cls0 coefficient table AB4[1376] (blocks 0..5) + max-feature
// GEMV with inline normalized maxes (blocks 6..37)
// ---------------------------------------------------------------------------
__global__ __launch_bounds__(256) void abgemv_k(const float* __restrict__ SUMS,
                                                const unsigned* __restrict__ MAXBu,
                                                float4* __restrict__ AB4,
                                                const unsigned short* __restrict__ Wmax,
                                                float* __restrict__ contrib,
                                                const float* g0, const float* b0,
                                                const float* g1, const float* b1,
                                                const float* g2, const float* b2,
                                                const float* g3, const float* b3) {
    int blk = blockIdx.x, t = threadIdx.x;
    if (blk < 6) {
        int ch = blk * 256 + t;
        if (ch >= 1376) return;
        float4 r;
        if (ch < 16) r = make_float4(1.f, 0.f, -__builtin_inff(), 0.f);
        else if (ch < 80) { float a, c; bncoef(SUMS, g0, b0, ch - 16, a, c); r = make_float4(a, c, 0.f, 0.f); }
        else if (ch < 208) { float a, c; bncoef(SUMS + 2048, g1, b1, ch - 80, a, c); r = make_float4(a, c, 0.f, 0.f); }
        else if (ch < 336) { float a, c; bncoef(SUMS + 4096, g2, b2, ch - 208, a, c); r = make_float4(a, c, 0.f, 0.f); }
        else if (ch < 1360) { float a, c; bncoef(SUMS + 6144, g3, b3, ch - 336, a, c); r = make_float4(a, c, 0.f, 0.f); }
        else r = make_float4(0.f, 0.f, 0.f, 0.f);
        AB4[ch] = r;
    } else {
        int i = blk - 6;
        int b = i >> 3;
        int cc = (i & 7) * 128;
        __shared__ float nm[128];
        if (t < 128) {
            int c = cc + t;
            float a, cf; bncoef(SUMS + 6144, g3, b3, c, a, cf);
            float raw = funflip(MAXBu[b * 1024 + c]);
            nm[t] = fmaxf(a * raw + cf, 0.f);
        }
        __syncthreads();
        int o = t;
        float acc = 0.f;
        for (int c = 0; c < 128; ++c)
            acc += h2f(Wmax[(size_t)(cc + c) * 256 + o]) * nm[c];
        atomicAdd(&contrib[b * 256 + o], acc);
    }
}

// ---------------------------------------------------------------------------
// cls0 finish: sum 4 fp16 K-split partials + contrib -> raw fp16 partial0 + stats
// ---------------------------------------------------------------------------
__global__ __launch_bounds__(256) void red4stat_k(unsigned short* __restrict__ Yh,
                                                  const float* __restrict__ contrib,
                                                  float* __restrict__ sums) {
    int o0 = blockIdx.x * 64;
    int m0 = blockIdx.y * 128;
    int t = threadIdx.x, ol = t & 63, mg = t >> 6;
    int b = m0 >> 11;
    float cb = contrib[b * 256 + o0 + ol];
    const size_t stride = (size_t)MM * 256;
    float s = 0.f, q = 0.f;
    unsigned short* p = Yh + (size_t)(m0 + mg) * 256 + o0 + ol;
    for (int i = 0; i < 32; ++i) {
        unsigned short* pp = p + (size_t)i * 4 * 256;
        float v = h2f(pp[0]) + h2f(pp[stride]) + h2f(pp[2 * stride]) + h2f(pp[3 * stride]) + cb;
        pp[0] = f2h(v);
        s += v; q += v * v;
    }
    __shared__ float ls[4][64], lq[4][64];
    ls[mg][ol] = s; lq[mg][ol] = q;
    __syncthreads();
    if (mg == 0) {
        s = ls[0][ol] + ls[1][ol] + ls[2][ol] + ls[3][ol];
        q = lq[0][ol] + lq[1][ol] + lq[2][ol] + lq[3][ol];
        atomicAdd(&sums[o0 + ol], s);
        atomicAdd(&sums[1024 + o0 + ol], q);
    }
}

// ---------------------------------------------------------------------------
extern "C" void kernel_launch(void* const* d_in, const int* in_sizes, int n_in,
                              void* d_out, int out_size, void* d_ws, size_t ws_size,
                              hipStream_t stream) {
    const float* in = (const float*)d_in[0];
    const float* pf0_w = (const float*)d_in[1];
    const float* pf_g[4] = {(const float*)d_in[2], (const float*)d_in[5], (const float*)d_in[8], (const float*)d_in[11]};
    const float* pf_b[4] = {(const float*)d_in[3], (const float*)d_in[6], (const float*)d_in[9], (const float*)d_in[12]};
    const float* pf_w[4] = {(const float*)d_in[1], (const float*)d_in[4], (const float*)d_in[7], (const float*)d_in[10]};
    const float* cls_w[3] = {(const float*)d_in[13], (const float*)d_in[16], (const float*)d_in[19]};
    const float* cls_g[3] = {(const float*)d_in[14], (const float*)d_in[17], (const float*)d_in[20]};
    const float* cls_b[3] = {(const float*)d_in[15], (const float*)d_in[18], (const float*)d_in[21]};
    const float* cls3_w = (const float*)d_in[22];
    const float* cls3_bias = (const float*)d_in[23];
    float* out = (float*)d_out;

    char* wsb = (char*)d_ws;
    float* ST = (float*)(wsb + 0);
    float4* PQ = (float4*)(wsb + 256);
    float* F0 = (float*)(wsb + 131328);
    float* SUMS = (float*)(wsb + 295168);
    unsigned* MAXBu = (unsigned*)(wsb + 352512);
    float* CONTRIB = (float*)(wsb + 368896);
    float4* AB4 = (float4*)(wsb + 372992);
    unsigned short* WB = (unsigned short*)(wsb + 411392);
    unsigned short* XCb = (unsigned short*)(wsb + 2180864);
    unsigned short* C1b = (unsigned short*)(wsb + 24725248);
    unsigned short* C2b = (unsigned short*)(wsb + 28919552);
    unsigned short* Yh = (unsigned short*)(wsb + 33113856);

    auto SL = [&](int s) { return SUMS + (size_t)s * 2048; };

    prep_k<<<976, 256, 0, stream>>>(in, pf_w[1], pf_w[2], pf_w[3], cls_w[0], cls_w[1], cls_w[2], cls3_w,
                                    WB, ST, (unsigned*)SUMS, XCb);
    point_k<<<MM / 256, 256, 0, stream>>>(in, ST, PQ, F0);
    alpha_k<<<MM / 8, 512, 0, stream>>>(PQ, F0);

    // pf0 raw -> XCb+16 with fused stats SL(0)
    pf0s_k<<<16, 256, 0, stream>>>(F0, pf0_w, XCb + 16, SL(0));
    // pf1: stage-norm SL(0); raw -> XCb+80; stats SL(1)
    mgemm64_k<1, 1><<<dim3(128, 2), 256, 0, stream>>>(XCb + 16, LDC, WB, 64, XCb + 80, LDC, 128, 64,
                                                      SL(1), SL(0), pf_g[0], pf_b[0]);
    // pf2: stage-norm SL(1); raw -> XCb+208; stats SL(2)
    mgemm64_k<1, 1><<<dim3(128, 2), 256, 0, stream>>>(XCb + 80, LDC, WB + 8192, 128, XCb + 208, LDC, 128, 128,
                                                      SL(2), SL(1), pf_g[1], pf_b[1]);
    // pf3: 128-tile; stage-norm SL(2); raw -> XCb+336; stats SL(3) + raw channel max
    mgemm128_k<1, 1, 1><<<dim3(64, 8, 1), 256, 0, stream>>>(XCb + 208, LDC, WB + 24576, 128, XCb + 336, LDC,
                                                            1024, 128, 128, SL(3), SL(2), pf_g[2], pf_b[2],
                                                            AB4, MAXBu);
    // fused coefficient table + max-feature GEMV
    abgemv_k<<<38, 256, 0, stream>>>(SUMS, MAXBu, AB4, WB + 614400, CONTRIB,
                                     pf_g[0], pf_b[0], pf_g[1], pf_b[1], pf_g[2], pf_b[2], pf_g[3], pf_b[3]);
    // cls0: 128-tile; stage-norm via AB4; K-split x4 raw fp16 partials
    mgemm128_k<2, 2, 0><<<dim3(64, 2, 4), 256, 0, stream>>>(XCb, LDC, WB + 155648, 1376, Yh, 256,
                                                            256, 1376, 352, SL(4), nullptr, nullptr, nullptr,
                                                            AB4, MAXBu);
    red4stat_k<<<dim3(4, 64), 256, 0, stream>>>(Yh, CONTRIB, SL(4));
    // cls1: stage-norm SL(4); raw -> C1b; stats SL(5)
    mgemm64_k<1, 1><<<dim3(128, 4), 256, 0, stream>>>(Yh, 256, WB + 507904, 256, C1b, 256, 256, 256,
                                                      SL(5), SL(4), cls_g[0], cls_b[0]);
    // cls2: stage-norm SL(5); raw -> C2b; stats SL(6)
    mgemm64_k<1, 1><<<dim3(128, 2), 256, 0, stream>>>(C1b, 256, WB + 507904 + 65536, 256, C2b, 128, 128, 256,
                                                      SL(6), SL(5), cls_g[1], cls_b[1]);
    // cls3: stage-norm SL(6); direct (b,50,n) output + bias
    mgemm64_k<3, 1><<<dim3(128, 1), 256, 0, stream>>>(C2b, 128, WB + 606208, 128, (void*)out, 0, 64, 128,
                                                      (float*)cls3_bias, SL(6), cls_g[2], cls_b[2]);

    (void)in_sizes; (void)n_in; (void)out_size; (void)ws_size;
}

// Round 21
// 145.076 us; speedup vs baseline: 1.0167x; 1.0167x over previous
//
#include <hip/hip_runtime.h>
#include <math.h>

#define BB 4
#define NN 2048
#define MM 8192
#define EPSF 1e-5f
#define LDC 1376   // concat stride: onehot16 | pf0 64 | pf1 128 | pf2 128 | pf3 1024 | pad16

typedef _Float16 half8 __attribute__((ext_vector_type(8)));
typedef float f32x4 __attribute__((ext_vector_type(4)));

__device__ __forceinline__ unsigned short f2h(float x) {
    _Float16 h = (_Float16)x;
    return __builtin_bit_cast(unsigned short, h);
}
__device__ __forceinline__ float h2f(unsigned short u) {
    return (float)__builtin_bit_cast(_Float16, u);
}
// order-preserving float<->unsigned for atomicMax over signed floats
__device__ __forceinline__ unsigned fflip(float x) {
    unsigned u = __builtin_bit_cast(unsigned, x);
    return (u >> 31) ? ~u : (u | 0x80000000u);
}
__device__ __forceinline__ float funflip(unsigned s) {
    unsigned u = (s >> 31) ? (s ^ 0x80000000u) : ~s;
    return __builtin_bit_cast(float, u);
}
#define FLIP_NEG_INF 0x007FFFFFu

__device__ __forceinline__ float angle3(float ux, float uy, float uz,
                                        float vx, float vy, float vz) {
    float crx = uy * vz - uz * vy;
    float cry = uz * vx - ux * vz;
    float crz = ux * vy - uy * vx;
    float s = sqrtf(crx * crx + cry * cry + crz * crz);
    float c = ux * vx + uy * vy + uz * vz;
    return atan2f(s, c);
}

// BN coefficient from a sums slice
__device__ __forceinline__ void bncoef(const float* __restrict__ sums,
                                       const float* __restrict__ g,
                                       const float* __restrict__ bb,
                                       int o, float& a, float& c) {
    float mu = sums[o] * (1.f / 8192.f);
    float var = sums[1024 + o] * (1.f / 8192.f) - mu * mu;
    var = fmaxf(var, 0.f);
    a = g[o] * (1.0f / sqrtf(var + EPSF));
    c = bb[o] - mu * a;
}

// ---------------------------------------------------------------------------
// fused preamble: wconv x4 (0..863) | stats (864..867) | init SUMS/MAXB/CONTRIB
// (868..943; MAXB gets flip(-inf)) | onehot+pad (944..975)
// ---------------------------------------------------------------------------
__global__ __launch_bounds__(256) void prep_k(const float* __restrict__ in,
                                              const float* __restrict__ w1, const float* __restrict__ w2,
                                              const float* __restrict__ w3, const float* __restrict__ w4,
                                              const float* __restrict__ w5, const float* __restrict__ w6,
                                              const float* __restrict__ w7,
                                              unsigned short* __restrict__ Wb,
                                              float* __restrict__ st,
                                              unsigned* __restrict__ zp,
                                              unsigned short* __restrict__ XCb) {
    int blk = blockIdx.x;
    int t = threadIdx.x;
    if (blk < 864) {
        int idx0 = blk * 1024 + t * 4;
        ushort4 r;
        unsigned short* rp = (unsigned short*)&r;
        #pragma unroll
        for (int e = 0; e < 4; ++e) {
            int idx = idx0 + e;
            unsigned short v;
            if (idx < 8192) v = f2h(w1[idx]);
            else if (idx < 24576) v = f2h(w2[idx - 8192]);
            else if (idx < 155648) v = f2h(w3[idx - 24576]);
            else if (idx < 507904) {
                int l = idx - 155648;
                int o = l / 1376, k = l - o * 1376;
                v = (k < 1360) ? f2h(w4[o * 2384 + k]) : (unsigned short)0;
            } else if (idx < 573440) v = f2h(w5[idx - 507904]);
            else if (idx < 606208) v = f2h(w6[idx - 573440]);
            else if (idx < 614400) {
                int l = idx - 606208;
                int o = l >> 7, k = l & 127;
                v = (o < 50) ? f2h(w7[o * 128 + k]) : (unsigned short)0;
            } else {
                int l = idx - 614400;
                int c = l >> 8, o = l & 255;
                v = (c < 1024) ? f2h(w4[o * 2384 + 1360 + c]) : (unsigned short)0;
            }
            rp[e] = v;
        }
        *(ushort4*)&Wb[idx0] = r;
    } else if (blk < 868) {
        int b = blk - 864;
        const float* base = in + (size_t)b * 22 * NN;
        float cs0 = 0.f, cs1 = 0.f, cs2 = 0.f, ns0 = 0.f, ns1 = 0.f, ns2 = 0.f;
        for (int n = t; n < NN; n += 256) {
            float cx = base[0 * NN + n], cy = base[1 * NN + n], cz = base[2 * NN + n];
            float nx = base[3 * NN + n], ny = base[4 * NN + n], nz = base[5 * NN + n];
            float inv = 1.0f / sqrtf(nx * nx + ny * ny + nz * nz);
            cs0 += cx; cs1 += cy; cs2 += cz;
            ns0 += nx * inv; ns1 += ny * inv; ns2 += nz * inv;
        }
        __shared__ float red[6][256];
        red[0][t] = cs0; red[1][t] = cs1; red[2][t] = cs2;
        red[3][t] = ns0; red[4][t] = ns1; red[5][t] = ns2;
        __syncthreads();
        for (int s = 128; s > 0; s >>= 1) {
            if (t < s) {
                #pragma unroll
                for (int i = 0; i < 6; ++i) red[i][t] += red[i][t + s];
            }
            __syncthreads();
        }
        if (t == 0) {
            float ccx = red[0][0] / (float)NN, ccy = red[1][0] / (float)NN, ccz = red[2][0] / (float)NN;
            float cnx = red[3][0] / (float)NN, cny = red[4][0] / (float)NN, cnz = red[5][0] / (float)NN;
            float inv = 1.0f / sqrtf(cnx * cnx + cny * cny + cnz * cnz);
            float* s9 = st + b * 16;
            s9[0] = ccx; s9[1] = ccy; s9[2] = ccz;
            s9[3] = cnx; s9[4] = cny; s9[5] = cnz;
            s9[6] = cnx * inv; s9[7] = cny * inv; s9[8] = cnz * inv;
        }
    } else if (blk < 944) {
        int idx = (blk - 868) * 256 + t;
        zp[idx] = (idx >= 14336 && idx < 18432) ? FLIP_NEG_INF : 0u;
    } else {
        int m = (blk - 944) * 256 + t;
        int b = m >> 11, n = m & (NN - 1);
        const float* src = in + (size_t)b * 22 * NN + 6 * NN + n;
        unsigned short vals[16];
        #pragma unroll
        for (int r = 0; r < 16; ++r) vals[r] = f2h(src[(size_t)r * NN]);
        ushort4* dst = (ushort4*)&XCb[(size_t)m * LDC];
        #pragma unroll
        for (int q = 0; q < 4; ++q)
            dst[q] = make_ushort4(vals[4 * q], vals[4 * q + 1], vals[4 * q + 2], vals[4 * q + 3]);
        ushort4 z = make_ushort4(0, 0, 0, 0);
        ushort4* pz = (ushort4*)&XCb[(size_t)m * LDC + 1360];
        pz[0] = z; pz[1] = z; pz[2] = z; pz[3] = z;
    }
}

// ---------------------------------------------------------------------------
// per-point PPF + packed projected vectors PQ = (x,y,z,|P|)
// ---------------------------------------------------------------------------
__global__ __launch_bounds__(256) void point_k(const float* __restrict__ in,
                                               const float* __restrict__ st,
                                               float4* __restrict__ PQ,
                                               float* __restrict__ F0) {
    int idx = blockIdx.x * 256 + threadIdx.x;
    int b = idx >> 11, n = idx & (NN - 1);
    const float* base = in + (size_t)b * 22 * NN;
    const float* s9 = st + b * 16;
    float cx = base[0 * NN + n], cy = base[1 * NN + n], cz = base[2 * NN + n];
    float nx = base[3 * NN + n], ny = base[4 * NN + n], nz = base[5 * NN + n];
    float inv = 1.0f / sqrtf(nx * nx + ny * ny + nz * nz);
    nx *= inv; ny *= inv; nz *= inv;
    float ccx = s9[0], ccy = s9[1], ccz = s9[2];
    float cnx = s9[3], cny = s9[4], cnz = s9[5];
    float ex = s9[6], ey = s9[7], ez = s9[8];
    float dx = cx - ccx, dy = cy - ccy, dz = cz - ccz;
    F0[0 * MM + idx] = angle3(cnx, cny, cnz, dx, dy, dz);
    F0[1 * MM + idx] = angle3(nx, ny, nz, dx, dy, dz);
    F0[2 * MM + idx] = angle3(cnx, cny, cnz, nx, ny, nz);
    F0[3 * MM + idx] = sqrtf(dx * dx + dy * dy + dz * dz);
    float dot = dx * ex + dy * ey + dz * ez;
    float px = dx - dot * cnx;
    float py = dy - dot * cny;
    float pz = dz - dot * cnz;
    PQ[idx] = make_float4(px, py, pz, sqrtf(px * px + py * py + pz * pz));
}

// ---------------------------------------------------------------------------
// per-row median via two-pass LDS histogram with algebraic fp16 key
// (R19 version — direct global loads; R20's shared-tile variant regressed:
// LDS port contention + 512-thread syncs outweighed the L1 savings).
// ---------------------------------------------------------------------------
__global__ __launch_bounds__(256) void alpha_k(const float4* __restrict__ PQ,
                                               float* __restrict__ F0) {
    __shared__ unsigned hist[4][256];
    int wv = threadIdx.x >> 6;
    int lane = threadIdx.x & 63;
    int row = blockIdx.x * 4 + wv;
    int b = row >> 11;
    const float4* base = PQ + (size_t)b * NN;
    float4 a = base[row & (NN - 1)];
    unsigned u[16];
    #pragma unroll
    for (int c = 0; c < 4; ++c) {
        #pragma unroll
        for (int j = 0; j < 4; ++j) {
            int s2 = c * 8 + j * 2;
            float4 bv0 = base[s2 * 64 + lane];
            float4 bv1 = base[(s2 + 1) * 64 + lane];
            float k0, k1;
            {
                float dc = a.x * bv0.x + a.y * bv0.y + a.z * bv0.z;
                float h = a.w * bv0.w;
                float rc = __builtin_amdgcn_rcpf(h + dc);
                k0 = (h - dc) * rc;
                if (k0 <= 2e-7f) k0 = __builtin_inff();
            }
            {
                float dc = a.x * bv1.x + a.y * bv1.y + a.z * bv1.z;
                float h = a.w * bv1.w;
                float rc = __builtin_amdgcn_rcpf(h + dc);
                k1 = (h - dc) * rc;
                if (k1 <= 2e-7f) k1 = __builtin_inff();
            }
            u[c * 4 + j] = (unsigned)f2h(k0) | ((unsigned)f2h(k1) << 16);
        }
        asm volatile("" ::: "memory");
    }
    unsigned* h = hist[wv];
    h[lane] = 0; h[lane + 64] = 0; h[lane + 128] = 0; h[lane + 192] = 0;
    __syncthreads();
    #pragma unroll
    for (int q = 0; q < 16; ++q) {
        atomicAdd(&h[(u[q] & 0xFFFFu) >> 7], 1u);
        atomicAdd(&h[u[q] >> 23], 1u);
    }
    __syncthreads();
    const unsigned K = 1023;
    unsigned h0 = h[4 * lane], h1 = h[4 * lane + 1], h2 = h[4 * lane + 2], h3 = h[4 * lane + 3];
    unsigned lsum = h0 + h1 + h2 + h3;
    unsigned inc = lsum;
    #pragma unroll
    for (int d = 1; d < 64; d <<= 1) {
        unsigned tv = __shfl_up(inc, d);
        if (lane >= d) inc += tv;
    }
    unsigned excl = inc - lsum;
    bool has = (excl <= K) && (K < inc);
    unsigned long long mask = __ballot(has);
    int L = __ffsll((long long)mask) - 1;
    unsigned packed = 0;
    if (has) {
        unsigned e = excl, Bq = 4 * lane;
        if (e + h0 <= K) { e += h0; Bq++;
            if (e + h1 <= K) { e += h1; Bq++;
                if (e + h2 <= K) { e += h2; Bq++; } } }
        packed = (Bq << 16) | e;
    }
    packed = __shfl(packed, L);
    unsigned B = packed >> 16;
    unsigned k2 = K - (packed & 0xFFFFu);
    __syncthreads();
    h[lane] = 0; h[lane + 64] = 0;
    __syncthreads();
    #pragma unroll
    for (int q = 0; q < 16; ++q) {
        unsigned lo = u[q] & 0xFFFFu, hi = u[q] >> 16;
        if ((lo >> 7) == B) atomicAdd(&h[lo & 127], 1u);
        if ((hi >> 7) == B) atomicAdd(&h[hi & 127], 1u);
    }
    __syncthreads();
    unsigned g0 = h[2 * lane], g1 = h[2 * lane + 1];
    unsigned ls2 = g0 + g1, inc2 = ls2;
    #pragma unroll
    for (int d = 1; d < 64; d <<= 1) {
        unsigned tv = __shfl_up(inc2, d);
        if (lane >= d) inc2 += tv;
    }
    unsigned excl2 = inc2 - ls2;
    bool has2 = (excl2 <= k2) && (k2 < inc2);
    unsigned long long m2 = __ballot(has2);
    int L2 = __ffsll((long long)m2) - 1;
    unsigned low = 0;
    if (has2) low = 2 * lane + ((excl2 + g0 <= k2) ? 1u : 0u);
    low = __shfl(low, L2);
    unsigned T = (B << 7) | low;
    if (lane == 0) {
        float lo = h2f((unsigned short)T);
        float hi = h2f((unsigned short)(T + 1));
        F0[4 * MM + row] = 2.0f * atanf(sqrtf(0.5f * (lo + hi)));
    }
}

// ---------------------------------------------------------------------------
// pf0 + fused BN stats: raw fp16 into XCb+16; stats -> sums.
// ---------------------------------------------------------------------------
__global__ __launch_bounds__(256) void pf0s_k(const float* __restrict__ F0,
                                              const float* __restrict__ W,
                                              unsigned short* __restrict__ dst,
                                              float* __restrict__ sums) {
    __shared__ float ws[320];
    int t = threadIdx.x;
    for (int i = t; i < 320; i += 256) ws[i] = W[i];
    __syncthreads();
    int ol = t & 63, mg = t >> 6;
    int m0 = blockIdx.x * 512;
    float w0 = ws[ol * 5], w1 = ws[ol * 5 + 1], w2 = ws[ol * 5 + 2], w3 = ws[ol * 5 + 3], w4 = ws[ol * 5 + 4];
    float s = 0.f, q = 0.f;
    for (int i = 0; i < 128; ++i) {
        int m = m0 + i * 4 + mg;
        float y = w0 * F0[m] + w1 * F0[MM + m] + w2 * F0[2 * MM + m]
                + w3 * F0[3 * MM + m] + w4 * F0[4 * MM + m];
        dst[(size_t)m * LDC + ol] = f2h(y);
        s += y; q += y * y;
    }
    __shared__ float ls[4][64], lq[4][64];
    ls[mg][ol] = s; lq[mg][ol] = q;
    __syncthreads();
    if (mg == 0) {
        s = ls[0][ol] + ls[1][ol] + ls[2][ol] + ls[3][ol];
        q = lq[0][ol] + lq[1][ol] + lq[2][ol] + lq[3][ol];
        atomicAdd(&sums[ol], s);
        atomicAdd(&sums[1024 + ol], q);
    }
}

// ---------------------------------------------------------------------------
// fp16 MFMA GEMM, 128x128 block tile, 4 waves (2x2), each wave 64x64
// (4x4 16x16x32 frags -> 16 MFMA : 8 ds_read_b128).
// TRANS: 0 none, 1 uniform (xs,xg,xb), 2 AB4 table (cls0).
// MODE: 1 raw fp16 out (yld) + stats [+DOMAX raw channel max]; 2 K-split partial.
// ---------------------------------------------------------------------------
template<int MODE, int TRANS, int DOMAX>
__global__ __launch_bounds__(256) void mgemm128_k(const unsigned short* __restrict__ X, int ldx,
                                                  const unsigned short* __restrict__ W, int ldw,
                                                  unsigned short* __restrict__ Yh, int yld, int Co, int K, int kchunk,
                                                  float* __restrict__ sums,
                                                  const float* __restrict__ xs, const float* __restrict__ xg,
                                                  const float* __restrict__ xb,
                                                  const float4* __restrict__ AB4,
                                                  unsigned* __restrict__ maxbu) {
    __shared__ unsigned short As[128 * 32];   // 8KB
    __shared__ unsigned short Bs[128 * 32];   // 8KB
    __shared__ float4 ABl[352];
    int t = threadIdx.x;
    int mBase = blockIdx.x * 128;
    int oBase = blockIdx.y * 128;
    int k0c = blockIdx.z * kchunk;
    int k1c = k0c + kchunk; if (k1c > K) k1c = K;
    if (TRANS == 1) {
        float* abf = (float*)ABl;
        for (int i = t; i < K; i += 256) {
            float a, c; bncoef(xs, xg, xb, i, a, c);
            abf[2 * i] = a; abf[2 * i + 1] = c;
        }
    } else if (TRANS == 2) {
        for (int i = t; i < k1c - k0c; i += 256) ABl[i] = AB4[k0c + i];
    }
    int lane = t & 63, w = t >> 6;
    int warpM = (w & 1) * 64, warpO = (w >> 1) * 64;
    f32x4 acc[4][4];
    #pragma unroll
    for (int i = 0; i < 4; ++i)
        #pragma unroll
        for (int j = 0; j < 4; ++j) acc[i][j] = (f32x4){0.f, 0.f, 0.f, 0.f};
    int lr = t >> 1;           // 0..127
    int lc = (t & 1) * 16;     // 0 or 16
    const unsigned short* Xp = X + (size_t)(mBase + lr) * ldx + lc;
    const unsigned short* Wp = W + (size_t)(oBase + lr) * ldw + lc;
    int ar0 = (warpM + (lane & 15)) * 32 + (lane >> 4) * 8;
    int br0 = (warpO + (lane & 15)) * 32 + (lane >> 4) * 8;
    uint4 xa0 = *(const uint4*)(Xp + k0c);
    uint4 xa1 = *(const uint4*)(Xp + k0c + 8);
    uint4 wb0 = *(const uint4*)(Wp + k0c);
    uint4 wb1 = *(const uint4*)(Wp + k0c + 8);
    for (int k = k0c; k < k1c; k += 32) {
        __syncthreads();
        uint4 xc0 = xa0, xc1 = xa1;
        if (TRANS == 1) {
            const float* abf = (const float*)ABl;
            unsigned short* p0 = (unsigned short*)&xc0;
            unsigned short* p1 = (unsigned short*)&xc1;
            int kb = k + lc;
            #pragma unroll
            for (int e = 0; e < 8; ++e) {
                p0[e] = f2h(fmaxf(abf[2 * (kb + e)] * h2f(p0[e]) + abf[2 * (kb + e) + 1], 0.f));
                p1[e] = f2h(fmaxf(abf[2 * (kb + 8 + e)] * h2f(p1[e]) + abf[2 * (kb + 8 + e) + 1], 0.f));
            }
        } else if (TRANS == 2) {
            unsigned short* p0 = (unsigned short*)&xc0;
            unsigned short* p1 = (unsigned short*)&xc1;
            int kb = k + lc - k0c;
            #pragma unroll
            for (int e = 0; e < 8; ++e) {
                float4 q0 = ABl[kb + e];
                float4 q1 = ABl[kb + 8 + e];
                p0[e] = f2h(fmaxf(q0.x * h2f(p0[e]) + q0.y, q0.z));
                p1[e] = f2h(fmaxf(q1.x * h2f(p1[e]) + q1.y, q1.z));
            }
        }
        *(uint4*)&As[lr * 32 + lc] = xc0;
        *(uint4*)&As[lr * 32 + lc + 8] = xc1;
        *(uint4*)&Bs[lr * 32 + lc] = wb0;
        *(uint4*)&Bs[lr * 32 + lc + 8] = wb1;
        if (k + 32 < k1c) {
            xa0 = *(const uint4*)(Xp + k + 32);
            xa1 = *(const uint4*)(Xp + k + 40);
            wb0 = *(const uint4*)(Wp + k + 32);
            wb1 = *(const uint4*)(Wp + k + 40);
        }
        __syncthreads();
        half8 af[4], bf[4];
        #pragma unroll
        for (int i = 0; i < 4; ++i) {
            af[i] = __builtin_bit_cast(half8, *(const uint4*)&As[ar0 + i * 16 * 32]);
            bf[i] = __builtin_bit_cast(half8, *(const uint4*)&Bs[br0 + i * 16 * 32]);
        }
        #pragma unroll
        for (int i = 0; i < 4; ++i)
            #pragma unroll
            for (int j = 0; j < 4; ++j)
                acc[i][j] = __builtin_amdgcn_mfma_f32_16x16x32_f16(af[i], bf[j], acc[i][j], 0, 0, 0);
    }
    unsigned short* Yp = Yh + (MODE == 2 ? (size_t)blockIdx.z * MM * yld : 0);
    #pragma unroll
    for (int i = 0; i < 4; ++i)
        #pragma unroll
        for (int j = 0; j < 4; ++j) {
            int m0 = mBase + warpM + i * 16 + (lane >> 4) * 4;
            int o = oBase + warpO + j * 16 + (lane & 15);
            #pragma unroll
            for (int r = 0; r < 4; ++r)
                Yp[(size_t)(m0 + r) * yld + o] = f2h(acc[i][j][r]);
        }
    if (MODE == 1) {
        __syncthreads();
        float* ssum = (float*)As;
        unsigned* smax = (unsigned*)As + 128;
        float* ssq = (float*)Bs;
        if (t < 128) { ssum[t] = 0.f; ssq[t] = 0.f; if (DOMAX) smax[t] = FLIP_NEG_INF; }
        __syncthreads();
        #pragma unroll
        for (int j = 0; j < 4; ++j) {
            int oc = warpO + j * 16 + (lane & 15);
            float s = 0.f, q = 0.f, mx = -__builtin_inff();
            #pragma unroll
            for (int i = 0; i < 4; ++i)
                #pragma unroll
                for (int r = 0; r < 4; ++r) {
                    float v = acc[i][j][r];
                    s += v; q += v * v; mx = fmaxf(mx, v);
                }
            atomicAdd(&ssum[oc], s);
            atomicAdd(&ssq[oc], q);
            if (DOMAX) atomicMax(&smax[oc], fflip(mx));
        }
        __syncthreads();
        if (t < 128) {
            atomicAdd(&sums[oBase + t], ssum[t]);
            atomicAdd(&sums[1024 + oBase + t], ssq[t]);
            if (DOMAX) atomicMax(&maxbu[(mBase >> 11) * 1024 + oBase + t], smax[t]);
        }
    }
}

// ---------------------------------------------------------------------------
// fp16 MFMA GEMM BM=64 BO=64 with staging-normalization.
// MODE 1: raw fp16 out (yld) + stats. MODE 3: direct (b,50,n) out + bias.
// ---------------------------------------------------------------------------
template<int MODE, int TRANS>
__global__ __launch_bounds__(256) void mgemm64_k(const unsigned short* __restrict__ X, int ldx,
                                                 const unsigned short* __restrict__ W, int ldw,
                                                 void* __restrict__ Yv, int yld, int Co, int K,
                                                 float* __restrict__ sums,
                                                 const float* __restrict__ xs, const float* __restrict__ xg,
                                                 const float* __restrict__ xb) {
    __shared__ unsigned short As[64 * 32];
    __shared__ unsigned short Bs[64 * 32];
    __shared__ float ABl[512];
    int t = threadIdx.x;
    int mBase = blockIdx.x * 64;
    int oBase = blockIdx.y * 64;
    if (TRANS == 1) {
        for (int i = t; i < K; i += 256) {
            float a, c; bncoef(xs, xg, xb, i, a, c);
            ABl[2 * i] = a; ABl[2 * i + 1] = c;
        }
    }
    int lane = t & 63, w = t >> 6;
    int warpM = (w & 1) * 32, warpO = (w >> 1) * 32;
    f32x4 acc[2][2];
    #pragma unroll
    for (int i = 0; i < 2; ++i)
        #pragma unroll
        for (int j = 0; j < 2; ++j) acc[i][j] = (f32x4){0.f, 0.f, 0.f, 0.f};
    int lr = t >> 2;
    int lc = (t & 3) * 8;
    const unsigned short* Xp = X + (size_t)(mBase + lr) * ldx + lc;
    const unsigned short* Wp = W + (size_t)(oBase + lr) * ldw + lc;
    int ar0 = (warpM + (lane & 15)) * 32 + (lane >> 4) * 8;
    int br0 = (warpO + (lane & 15)) * 32 + (lane >> 4) * 8;
    uint4 xa = *(const uint4*)(Xp);
    uint4 wb = *(const uint4*)(Wp);
    for (int k = 0; k < K; k += 32) {
        __syncthreads();
        uint4 xc = xa;
        if (TRANS == 1) {
            unsigned short* p = (unsigned short*)&xc;
            int kb = k + lc;
            #pragma unroll
            for (int e = 0; e < 8; ++e)
                p[e] = f2h(fmaxf(ABl[2 * (kb + e)] * h2f(p[e]) + ABl[2 * (kb + e) + 1], 0.f));
        }
        *(uint4*)&As[lr * 32 + lc] = xc;
        *(uint4*)&Bs[lr * 32 + lc] = wb;
        if (k + 32 < K) {
            xa = *(const uint4*)(Xp + k + 32);
            wb = *(const uint4*)(Wp + k + 32);
        }
        __syncthreads();
        half8 a0 = __builtin_bit_cast(half8, *(const uint4*)&As[ar0]);
        half8 a1 = __builtin_bit_cast(half8, *(const uint4*)&As[ar0 + 16 * 32]);
        half8 b0 = __builtin_bit_cast(half8, *(const uint4*)&Bs[br0]);
        half8 b1 = __builtin_bit_cast(half8, *(const uint4*)&Bs[br0 + 16 * 32]);
        acc[0][0] = __builtin_amdgcn_mfma_f32_16x16x32_f16(a0, b0, acc[0][0], 0, 0, 0);
        acc[0][1] = __builtin_amdgcn_mfma_f32_16x16x32_f16(a0, b1, acc[0][1], 0, 0, 0);
        acc[1][0] = __builtin_amdgcn_mfma_f32_16x16x32_f16(a1, b0, acc[1][0], 0, 0, 0);
        acc[1][1] = __builtin_amdgcn_mfma_f32_16x16x32_f16(a1, b1, acc[1][1], 0, 0, 0);
    }
    if (MODE == 3) {
        float* outp = (float*)Yv;
        #pragma unroll
        for (int i = 0; i < 2; ++i)
            #pragma unroll
            for (int j = 0; j < 2; ++j) {
                int m0 = mBase + warpM + i * 16 + (lane >> 4) * 4;
                int o = oBase + warpO + j * 16 + (lane & 15);
                if (o < 50) {
                    int bb2 = m0 >> 11, n = m0 & (NN - 1);
                    float bi = sums[o];
                    float4 v = make_float4(acc[i][j][0] + bi, acc[i][j][1] + bi,
                                           acc[i][j][2] + bi, acc[i][j][3] + bi);
                    *(float4*)&outp[((size_t)bb2 * 50 + o) * NN + n] = v;
                }
            }
    } else {
        unsigned short* Yh = (unsigned short*)Yv;
        #pragma unroll
        for (int i = 0; i < 2; ++i)
            #pragma unroll
            for (int j = 0; j < 2; ++j) {
                int m0 = mBase + warpM + i * 16 + (lane >> 4) * 4;
                int o = oBase + warpO + j * 16 + (lane & 15);
                #pragma unroll
                for (int r = 0; r < 4; ++r)
                    Yh[(size_t)(m0 + r) * yld + o] = f2h(acc[i][j][r]);
            }
        __syncthreads();
        float* ssum = (float*)As;
        float* ssq = (float*)Bs;
        if (t < 64) { ssum[t] = 0.f; ssq[t] = 0.f; }
        __syncthreads();
        #pragma unroll
        for (int j = 0; j < 2; ++j) {
            int oc = warpO + j * 16 + (lane & 15);
            float s = 0.f, q = 0.f;
            #pragma unroll
            for (int i = 0; i < 2; ++i)
                #pragma unroll
                for (int r = 0; r < 4; ++r) { float v = acc[i][j][r]; s += v; q += v * v; }
            atomicAdd(&ssum[oc], s);
            atomicAdd(&ssq[oc], q);
        }
        __syncthreads();
        if (t < 64) {
            atomicAdd(&sums[oBase + t], ssum[t]);
            atomicAdd(&sums[1024 + oBase + t], ssq[t]);
        }
    }
}

// ---------------------------------------------------------------------------
// fused: build cls0 coefficient table AB4[1376] (blocks 0..5) + max-feature
// GEMV with inline normalized maxes (blocks 6..37)
// ---------------------------------------------------------------------------
__global__ __launch_bounds__(256) void abgemv_k(const float* __restrict__ SUMS,
                                                const unsigned* __restrict__ MAXBu,
                                                float4* __restrict__ AB4,
                                                const unsigned short* __restrict__ Wmax,
                                                float* __restrict__ contrib,
                                                const float* g0, const float* b0,
                                                const float* g1, const float* b1,
                                                const float* g2, const float* b2,
                                                const float* g3, const float* b3) {
    int blk = blockIdx.x, t = threadIdx.x;
    if (blk < 6) {
        int ch = blk * 256 + t;
        if (ch >= 1376) return;
        float4 r;
        if (ch < 16) r = make_float4(1.f, 0.f, -__builtin_inff(), 0.f);
        else if (ch < 80) { float a, c; bncoef(SUMS, g0, b0, ch - 16, a, c); r = make_float4(a, c, 0.f, 0.f); }
        else if (ch < 208) { float a, c; bncoef(SUMS + 2048, g1, b1, ch - 80, a, c); r = make_float4(a, c, 0.f, 0.f); }
        else if (ch < 336) { float a, c; bncoef(SUMS + 4096, g2, b2, ch - 208, a, c); r = make_float4(a, c, 0.f, 0.f); }
        else if (ch < 1360) { float a, c; bncoef(SUMS + 6144, g3, b3, ch - 336, a, c); r = make_float4(a, c, 0.f, 0.f); }
        else r = make_float4(0.f, 0.f, 0.f, 0.f);
        AB4[ch] = r;
    } else {
        int i = blk - 6;
        int b = i >> 3;
        int cc = (i & 7) * 128;
        __shared__ float nm[128];
        if (t < 128) {
            int c = cc + t;
            float a, cf; bncoef(SUMS + 6144, g3, b3, c, a, cf);
            float raw = funflip(MAXBu[b * 1024 + c]);
            nm[t] = fmaxf(a * raw + cf, 0.f);
        }
        __syncthreads();
        int o = t;
        float acc = 0.f;
        for (int c = 0; c < 128; ++c)
            acc += h2f(Wmax[(size_t)(cc + c) * 256 + o]) * nm[c];
        atomicAdd(&contrib[b * 256 + o], acc);
    }
}

// ---------------------------------------------------------------------------
// cls0 finish: sum 4 fp16 K-split partials + contrib -> raw fp16 partial0 + stats
// ---------------------------------------------------------------------------
__global__ __launch_bounds__(256) void red4stat_k(unsigned short* __restrict__ Yh,
                                                  const float* __restrict__ contrib,
                                                  float* __restrict__ sums) {
    int o0 = blockIdx.x * 64;
    int m0 = blockIdx.y * 128;
    int t = threadIdx.x, ol = t & 63, mg = t >> 6;
    int b = m0 >> 11;
    float cb = contrib[b * 256 + o0 + ol];
    const size_t stride = (size_t)MM * 256;
    float s = 0.f, q = 0.f;
    unsigned short* p = Yh + (size_t)(m0 + mg) * 256 + o0 + ol;
    for (int i = 0; i < 32; ++i) {
        unsigned short* pp = p + (size_t)i * 4 * 256;
        float v = h2f(pp[0]) + h2f(pp[stride]) + h2f(pp[2 * stride]) + h2f(pp[3 * stride]) + cb;
        pp[0] = f2h(v);
        s += v; q += v * v;
    }
    __shared__ float ls[4][64], lq[4][64];
    ls[mg][ol] = s; lq[mg][ol] = q;
    __syncthreads();
    if (mg == 0) {
        s = ls[0][ol] + ls[1][ol] + ls[2][ol] + ls[3][ol];
        q = lq[0][ol] + lq[1][ol] + lq[2][ol] + lq[3][ol];
        atomicAdd(&sums[o0 + ol], s);
        atomicAdd(&sums[1024 + o0 + ol], q);
    }
}

// ---------------------------------------------------------------------------
extern "C" void kernel_launch(void* const* d_in, const int* in_sizes, int n_in,
                              void* d_out, int out_size, void* d_ws, size_t ws_size,
                              hipStream_t stream) {
    const float* in = (const float*)d_in[0];
    const float* pf0_w = (const float*)d_in[1];
    const float* pf_g[4] = {(const float*)d_in[2], (const float*)d_in[5], (const float*)d_in[8], (const float*)d_in[11]};
    const float* pf_b[4] = {(const float*)d_in[3], (const float*)d_in[6], (const float*)d_in[9], (const float*)d_in[12]};
    const float* pf_w[4] = {(const float*)d_in[1], (const float*)d_in[4], (const float*)d_in[7], (const float*)d_in[10]};
    const float* cls_w[3] = {(const float*)d_in[13], (const float*)d_in[16], (const float*)d_in[19]};
    const float* cls_g[3] = {(const float*)d_in[14], (const float*)d_in[17], (const float*)d_in[20]};
    const float* cls_b[3] = {(const float*)d_in[15], (const float*)d_in[18], (const float*)d_in[21]};
    const float* cls3_w = (const float*)d_in[22];
    const float* cls3_bias = (const float*)d_in[23];
    float* out = (float*)d_out;

    char* wsb = (char*)d_ws;
    float* ST = (float*)(wsb + 0);
    float4* PQ = (float4*)(wsb + 256);
    float* F0 = (float*)(wsb + 131328);
    float* SUMS = (float*)(wsb + 295168);
    unsigned* MAXBu = (unsigned*)(wsb + 352512);
    float* CONTRIB = (float*)(wsb + 368896);
    float4* AB4 = (float4*)(wsb + 372992);
    unsigned short* WB = (unsigned short*)(wsb + 411392);
    unsigned short* XCb = (unsigned short*)(wsb + 2180864);
    unsigned short* C1b = (unsigned short*)(wsb + 24725248);
    unsigned short* C2b = (unsigned short*)(wsb + 28919552);
    unsigned short* Yh = (unsigned short*)(wsb + 33113856);

    auto SL = [&](int s) { return SUMS + (size_t)s * 2048; };

    prep_k<<<976, 256, 0, stream>>>(in, pf_w[1], pf_w[2], pf_w[3], cls_w[0], cls_w[1], cls_w[2], cls3_w,
                                    WB, ST, (unsigned*)SUMS, XCb);
    point_k<<<MM / 256, 256, 0, stream>>>(in, ST, PQ, F0);
    alpha_k<<<MM / 4, 256, 0, stream>>>(PQ, F0);

    // pf0 raw -> XCb+16 with fused stats SL(0)
    pf0s_k<<<16, 256, 0, stream>>>(F0, pf0_w, XCb + 16, SL(0));
    // pf1: stage-norm SL(0); raw -> XCb+80; stats SL(1)
    mgemm64_k<1, 1><<<dim3(128, 2), 256, 0, stream>>>(XCb + 16, LDC, WB, 64, XCb + 80, LDC, 128, 64,
                                                      SL(1), SL(0), pf_g[0], pf_b[0]);
    // pf2: stage-norm SL(1); raw -> XCb+208; stats SL(2)
    mgemm64_k<1, 1><<<dim3(128, 2), 256, 0, stream>>>(XCb + 80, LDC, WB + 8192, 128, XCb + 208, LDC, 128, 128,
                                                      SL(2), SL(1), pf_g[1], pf_b[1]);
    // pf3: 128-tile; stage-norm SL(2); raw -> XCb+336; stats SL(3) + raw channel max
    mgemm128_k<1, 1, 1><<<dim3(64, 8, 1), 256, 0, stream>>>(XCb + 208, LDC, WB + 24576, 128, XCb + 336, LDC,
                                                            1024, 128, 128, SL(3), SL(2), pf_g[2], pf_b[2],
                                                            AB4, MAXBu);
    // fused coefficient table + max-feature GEMV
    abgemv_k<<<38, 256, 0, stream>>>(SUMS, MAXBu, AB4, WB + 614400, CONTRIB,
                                     pf_g[0], pf_b[0], pf_g[1], pf_b[1], pf_g[2], pf_b[2], pf_g[3], pf_b[3]);
    // cls0: 128-tile; stage-norm via AB4; K-split x4 raw fp16 partials
    mgemm128_k<2, 2, 0><<<dim3(64, 2, 4), 256, 0, stream>>>(XCb, LDC, WB + 155648, 1376, Yh, 256,
                                                            256, 1376, 352, SL(4), nullptr, nullptr, nullptr,
                                                            AB4, MAXBu);
    red4stat_k<<<dim3(4, 64), 256, 0, stream>>>(Yh, CONTRIB, SL(4));
    // cls1: stage-norm SL(4); raw -> C1b; stats SL(5)
    mgemm64_k<1, 1><<<dim3(128, 4), 256, 0, stream>>>(Yh, 256, WB + 507904, 256, C1b, 256, 256, 256,
                                                      SL(5), SL(4), cls_g[0], cls_b[0]);
    // cls2: stage-norm SL(5); raw -> C2b; stats SL(6)
    mgemm64_k<1, 1><<<dim3(128, 2), 256, 0, stream>>>(C1b, 256, WB + 507904 + 65536, 256, C2b, 128, 128, 256,
                                                      SL(6), SL(5), cls_g[1], cls_b[1]);
    // cls3: stage-norm SL(6); direct (b,50,n) output + bias
    mgemm64_k<3, 1><<<dim3(128, 1), 256, 0, stream>>>(C2b, 128, WB + 606208, 128, (void*)out, 0, 64, 128,
                                                      (float*)cls3_bias, SL(6), cls_g[2], cls_b[2]);

    (void)in_sizes; (void)n_in; (void)out_size; (void)ws_size;
}